// Round 15
// baseline (601.740 us; speedup 1.0000x reference)
//
#include <hip/hip_runtime.h>

#define AS1 __attribute__((address_space(1)))
#define AS3 __attribute__((address_space(3)))

typedef __attribute__((ext_vector_type(8))) short s16x8;
typedef __attribute__((ext_vector_type(4))) float f32x4;
typedef __attribute__((ext_vector_type(4))) unsigned short u16x4;
typedef __attribute__((ext_vector_type(8))) unsigned short u16x8;

#define MFMA16(a, b, c) __builtin_amdgcn_mfma_f32_16x16x32_bf16(a, b, c, 0, 0, 0)

static __device__ __forceinline__ unsigned short f2bf(float f) {
  unsigned u = __builtin_bit_cast(unsigned, f);
  u += 0x7fffu + ((u >> 16) & 1u);
  return (unsigned short)(u >> 16);
}

static __device__ __forceinline__ void gll16(const unsigned short* g, char* l) {
  __builtin_amdgcn_global_load_lds((const AS1 void*)g, (AS3 void*)l, 16, 0, 0);
}

#define BAR() asm volatile("s_barrier" ::: "memory")
#define WAITV(N) asm volatile("s_waitcnt vmcnt(" #N ")" ::: "memory")
#define FENCE() asm volatile("" ::: "memory")

// ===========================================================================
// 256x256 8-phase pipelined GEMM core (C = A[M,K] @ B[N,K]^T), bf16, f32 acc.
// (r10-proven schedule)
// ===========================================================================
__device__ __forceinline__ void gemm256_pipe(const unsigned short* __restrict__ A0, int lda,
                                             const unsigned short* __restrict__ B0, int ldb,
                                             int NT2, char* lds, f32x4 (&acc)[8][4]) {
  const int t = threadIdx.x;
  const int lane = t & 63, w = t >> 6, g = lane >> 4, l15 = lane & 15;
  const int wm = w >> 2, wn = w & 3;
  char* const A_lds[2] = {lds, lds + 65536};
  char* const B_lds[2] = {lds + 32768, lds + 98304};
  s16x8 af[2][4], bfr[2][4];

  const int rl = t >> 3, sl = t & 7;
  const unsigned short* aB = A0 + (size_t)rl * lda + ((sl ^ (rl & 7)) << 3);
  const unsigned short* bB = B0 + (size_t)rl * ldb + ((sl ^ (rl & 7)) << 3);
  const int woff = w << 10;

  char* pA[2][2];
  char* pB[2][2];
#pragma unroll
  for (int b = 0; b < 2; ++b)
#pragma unroll
    for (int kk = 0; kk < 2; ++kk) {
      pA[b][kk] = lds + b * 65536 + (wm * 64 + l15) * 128 + (((kk * 4 + g) ^ (l15 & 7)) << 4);
      pB[b][kk] = lds + 32768 + b * 65536 + (wn * 32 + l15) * 128 + (((kk * 4 + g) ^ (l15 & 7)) << 4);
    }

#define STGA(BUF, H, PTR)                                                                \
  do {                                                                                   \
    gll16((PTR) + (size_t)((H)*128) * lda, A_lds[BUF] + woff + (H)*16384);               \
    gll16((PTR) + (size_t)((H)*128 + 64) * lda, A_lds[BUF] + woff + (H)*16384 + 8192);   \
  } while (0)
#define STGB(BUF, H, PTR)                                                                \
  do {                                                                                   \
    gll16((PTR) + (size_t)((H)*128) * ldb, B_lds[BUF] + woff + (H)*16384);               \
    gll16((PTR) + (size_t)((H)*128 + 64) * ldb, B_lds[BUF] + woff + (H)*16384 + 8192);   \
  } while (0)

#define LDAQ(BUF, QH)                                                                    \
  do {                                                                                   \
    _Pragma("unroll") for (int mi = 0; mi < 4; ++mi)                                     \
        _Pragma("unroll") for (int kk = 0; kk < 2; ++kk)                                 \
            af[kk][mi] = *(const s16x8*)(pA[BUF][kk] + (QH)*16384 + mi * 2048);          \
  } while (0)
#define LDBP(BUF, NH)                                                                    \
  do {                                                                                   \
    _Pragma("unroll") for (int ni = 0; ni < 2; ++ni)                                     \
        _Pragma("unroll") for (int kk = 0; kk < 2; ++kk)                                 \
            bfr[kk][(NH)*2 + ni] =                                                       \
                *(const s16x8*)(pB[BUF][kk] + (NH)*16384 + ni * 2048);                   \
  } while (0)
#define MQUAD(QH, NH)                                                                    \
  do {                                                                                   \
    __builtin_amdgcn_s_setprio(1);                                                       \
    _Pragma("unroll") for (int kk = 0; kk < 2; ++kk)                                     \
        _Pragma("unroll") for (int mi = 0; mi < 4; ++mi)                                 \
            _Pragma("unroll") for (int ni = 0; ni < 2; ++ni)                             \
                acc[(QH)*4 + mi][(NH)*2 + ni] =                                          \
        MFMA16(af[kk][mi], bfr[kk][(NH)*2 + ni], acc[(QH)*4 + mi][(NH)*2 + ni]);         \
    __builtin_amdgcn_s_setprio(0);                                                       \
  } while (0)

  STGA(0, 0, aB);
  STGB(0, 0, bB);
  STGB(0, 1, bB);
  STGA(0, 1, aB);
  STGA(1, 0, aB + 64);
  STGB(1, 0, bB + 64);
  STGB(1, 1, bB + 64);
  STGA(1, 1, aB + 64);
  WAITV(8);
  BAR();

  for (int it = 0; it < NT2; ++it) {
    const bool pf = (it + 1 < NT2);
    const unsigned short* aN = aB + it * 128 + 128;
    const unsigned short* bN = bB + it * 128 + 128;
    LDAQ(0, 0);
    LDBP(0, 0);
    MQUAD(0, 0);
    BAR();
    LDBP(0, 1);
    if (pf) { STGA(0, 0, aN); STGB(0, 0, bN); }
    MQUAD(0, 1);
    BAR();
    LDAQ(0, 1);
    if (pf) STGB(0, 1, bN);
    MQUAD(1, 0);
    BAR();
    if (pf) STGA(0, 1, aN);
    MQUAD(1, 1);
    if (pf) WAITV(8);
    else WAITV(0);
    BAR();
    LDAQ(1, 0);
    LDBP(1, 0);
    MQUAD(0, 0);
    BAR();
    LDBP(1, 1);
    if (pf) { STGA(1, 0, aN + 64); STGB(1, 0, bN + 64); }
    MQUAD(0, 1);
    BAR();
    LDAQ(1, 1);
    if (pf) STGB(1, 1, bN + 64);
    MQUAD(1, 0);
    BAR();
    if (pf) STGA(1, 1, aN + 64);
    MQUAD(1, 1);
    if (pf) WAITV(8);
    BAR();
  }
#undef STGA
#undef STGB
#undef LDAQ
#undef LDBP
#undef MQUAD
}

// C mapping: row = QH*128 + wm*64 + (mq&3)*16 + g*4 + r   (mq = QH*4 + mi)
//            col = NH*128 + wn*32 + (nf&1)*16 + l15        (nf = NH*2 + ni)

// ---------------------------------------------------------------------------
// Q projection (8-phase 256^2): Qb = (x @ Wq^T + bq) * (log2e/8), bf16 out.
// ---------------------------------------------------------------------------
__global__ __launch_bounds__(512, 2) void k_gemm_q(const unsigned short* __restrict__ xb,
                                                   const unsigned short* __restrict__ Wqt,
                                                   const float* __restrict__ biasq,
                                                   unsigned short* __restrict__ Qb) {
  __shared__ __align__(16) char lds[131072];
  f32x4 acc[8][4];
#pragma unroll
  for (int i = 0; i < 8; ++i)
#pragma unroll
    for (int j = 0; j < 4; ++j) acc[i][j] = f32x4{0.f, 0.f, 0.f, 0.f};
  int bid = blockIdx.y * 4 + blockIdx.x;  // nwg = 512
  bid = (bid & 7) * 64 + (bid >> 3);
  const int bn = bid & 3, bm = bid >> 2;
  gemm256_pipe(xb + (size_t)bm * 256 * 1024, 1024, Wqt + (size_t)bn * 256 * 1024, 1024, 8, lds, acc);

  const int t = threadIdx.x, lane = t & 63, w = t >> 6, g = lane >> 4, l15 = lane & 15;
  const int wm = w >> 2, wn = w & 3;
  const float QSC = 0.1803368801111204f;  // log2e / 8
#pragma unroll
  for (int nf = 0; nf < 4; ++nf) {
    const int n = bn * 256 + (nf >> 1) * 128 + wn * 32 + (nf & 1) * 16 + l15;
    const float bias = biasq[n];
#pragma unroll
    for (int mq = 0; mq < 8; ++mq) {
      const int m0 = bm * 256 + (mq >> 2) * 128 + wm * 64 + (mq & 3) * 16 + g * 4;
      const f32x4 v = acc[mq][nf];
#pragma unroll
      for (int r = 0; r < 4; ++r) Qb[(size_t)(m0 + r) * 1024 + n] = f2bf((v[r] + bias) * QSC);
    }
  }
}

// ---------------------------------------------------------------------------
// Output projection (8-phase 256^2): f32 out = AO_bf16 @ Wo^T + bo
// ---------------------------------------------------------------------------
__global__ __launch_bounds__(512, 2) void k_gemm_out(const unsigned short* __restrict__ AO,
                                                     const unsigned short* __restrict__ Wot,
                                                     const float* __restrict__ bo,
                                                     float* __restrict__ out) {
  __shared__ __align__(16) char lds[131072];
  f32x4 acc[8][4];
#pragma unroll
  for (int i = 0; i < 8; ++i)
#pragma unroll
    for (int j = 0; j < 4; ++j) acc[i][j] = f32x4{0.f, 0.f, 0.f, 0.f};
  int bid = blockIdx.y * 4 + blockIdx.x;  // nwg = 512
  bid = (bid & 7) * 64 + (bid >> 3);
  const int bn = bid & 3, bm = bid >> 2;
  gemm256_pipe(AO + (size_t)bm * 256 * 1024, 1024, Wot + (size_t)bn * 256 * 1024, 1024, 8, lds, acc);

  const int t = threadIdx.x, lane = t & 63, w = t >> 6, g = lane >> 4, l15 = lane & 15;
  const int wm = w >> 2, wn = w & 3;
#pragma unroll
  for (int nf = 0; nf < 4; ++nf) {
    const int n = bn * 256 + (nf >> 1) * 128 + wn * 32 + (nf & 1) * 16 + l15;
    const float bias = bo[n];
#pragma unroll
    for (int mq = 0; mq < 8; ++mq) {
      const int m0 = bm * 256 + (mq >> 2) * 128 + wm * 64 + (mq & 3) * 16 + g * 4;
      const f32x4 v = acc[mq][nf];
#pragma unroll
      for (int r = 0; r < 4; ++r) out[(size_t)(m0 + r) * 1024 + n] = v[r] + bias;
    }
  }
}

// ---------------------------------------------------------------------------
// xE/xF split-K on the 8-phase 256^2 core. Grid (4 n-tiles, 1, 64 z) = 256
// blocks = 1/CU. z = ks*16 + (b*2+ef); K-chunk 1024 (NT2=8); f32 partials.
// ---------------------------------------------------------------------------
__global__ __launch_bounds__(512, 2) void k_gemm_xef(const unsigned short* __restrict__ Et,
                                                     const unsigned short* __restrict__ Ft,
                                                     const unsigned short* __restrict__ xbT,
                                                     float* __restrict__ pxef) {
  __shared__ __align__(16) char lds[131072];
  f32x4 acc[8][4];
#pragma unroll
  for (int i = 0; i < 8; ++i)
#pragma unroll
    for (int j = 0; j < 4; ++j) acc[i][j] = f32x4{0.f, 0.f, 0.f, 0.f};
  const int z = blockIdx.z;
  const int ks = z >> 4, pair = z & 15, b = pair >> 1, ef = pair & 1;
  const unsigned short* Ab = (ef ? Ft : Et) + ks * 1024;  // [256 kp][4096], chunk col base
  const unsigned short* Bb = xbT + (size_t)b * 4194304 + (size_t)blockIdx.x * 256 * 4096 + ks * 1024;
  gemm256_pipe(Ab, 4096, Bb, 4096, 8, lds, acc);

  const int t = threadIdx.x, lane = t & 63, w = t >> 6, g = lane >> 4, l15 = lane & 15;
  const int wm = w >> 2, wn = w & 3;
  float* C = pxef + (size_t)z * 262144;
#pragma unroll
  for (int nf = 0; nf < 4; ++nf) {
    const int n = blockIdx.x * 256 + (nf >> 1) * 128 + wn * 32 + (nf & 1) * 16 + l15;
#pragma unroll
    for (int mq = 0; mq < 8; ++mq) {
      const int m0 = (mq >> 2) * 128 + wm * 64 + (mq & 3) * 16 + g * 4;
      const f32x4 v = acc[mq][nf];
#pragma unroll
      for (int r = 0; r < 4; ++r) C[(size_t)(m0 + r) * 1024 + n] = v[r];
    }
  }
}

// ---------------------------------------------------------------------------
// Split-K reduce: xEF[j] = bf16(sum_ks pxef[ks][j]), vectorized x4.
// ---------------------------------------------------------------------------
__global__ __launch_bounds__(256) void k_xef_red(const float* __restrict__ pxef,
                                                 unsigned short* __restrict__ xEF) {
  const int j = (blockIdx.x * 256 + threadIdx.x) * 4;
  f32x4 s = *(const f32x4*)(pxef + j);
#pragma unroll
  for (int ks = 1; ks < 4; ++ks) {
    const f32x4 p = *(const f32x4*)(pxef + (size_t)ks * 4194304 + j);
#pragma unroll
    for (int r = 0; r < 4; ++r) s[r] += p[r];
  }
  u16x4 o;
#pragma unroll
  for (int r = 0; r < 4; ++r) o[r] = f2bf(s[r]);
  *(u16x4*)(xEF + j) = o;
}

// ===========================================================================
// 128x128 2-barrier GEMM core (kpvp2 only)
// ===========================================================================
__device__ __forceinline__ void gemm_tile(const unsigned short* __restrict__ Ab, int lda,
                                          const unsigned short* __restrict__ Bb, int ldb,
                                          int Kc, char* lds, f32x4 (&acc)[4][4]) {
  const int t = threadIdx.x;
  const int lane = t & 63, w = t >> 6, g = lane >> 4, l15 = lane & 15;
  const int wm = w >> 1, wn = w & 1;
  char* As = lds;
  char* Bs = lds + 16384;
  for (int ks = 0; ks < Kc; ks += 64) {
    __syncthreads();
#pragma unroll
    for (int i = 0; i < 4; ++i) {
      const int c = i * 256 + t, row = c >> 3, sl = c & 7;
      const int col = ks + ((sl ^ (row & 7)) << 3);
      const int ubase = (i * 256 + w * 64) << 4;
      gll16(Ab + (size_t)row * lda + col, As + ubase);
      gll16(Bb + (size_t)row * ldb + col, Bs + ubase);
    }
    __syncthreads();
    s16x8 af[2][4], bfr[2][4];
#pragma unroll
    for (int kk = 0; kk < 2; ++kk)
#pragma unroll
      for (int x4 = 0; x4 < 4; ++x4) {
        const int ra = wm * 64 + x4 * 16 + l15;
        const int rb = wn * 64 + x4 * 16 + l15;
        af[kk][x4] = *(const s16x8*)(As + ra * 128 + ((((kk << 2) + g) ^ (ra & 7)) << 4));
        bfr[kk][x4] = *(const s16x8*)(Bs + rb * 128 + ((((kk << 2) + g) ^ (rb & 7)) << 4));
      }
#pragma unroll
    for (int kk = 0; kk < 2; ++kk)
#pragma unroll
      for (int mt = 0; mt < 4; ++mt)
#pragma unroll
        for (int nt = 0; nt < 4; ++nt)
          acc[mt][nt] = MFMA16(af[kk][mt], bfr[kk][nt], acc[mt][nt]);
  }
}

// ---------------------------------------------------------------------------
// Kp/Vp: per (b, kv): C[256,1024] = xEF_b,kv @ W{k,v}t^T + sEF[kp]*b{k,v}[d].
// ---------------------------------------------------------------------------
__global__ __launch_bounds__(256) void k_kpvp2(const unsigned short* __restrict__ xEF,
                                               const unsigned short* __restrict__ Wqkvt,
                                               const float* __restrict__ biasq,
                                               const float* __restrict__ sEF,
                                               unsigned short* __restrict__ Kp,
                                               unsigned short* __restrict__ VpT) {
  __shared__ __align__(16) char lds[32768];
  f32x4 acc[4][4];
#pragma unroll
  for (int i = 0; i < 4; ++i)
#pragma unroll
    for (int j = 0; j < 4; ++j) acc[i][j] = f32x4{0.f, 0.f, 0.f, 0.f};
  const int b = blockIdx.z >> 1, kv = blockIdx.z & 1;
  const unsigned short* Ab = xEF + (size_t)(b * 2 + kv) * 262144 + blockIdx.y * 128 * 1024;
  const unsigned short* Bb = Wqkvt + (size_t)(1 + kv) * 1048576 + blockIdx.x * 128 * 1024;
  gemm_tile(Ab, 1024, Bb, 1024, 1024, lds, acc);

  const int t = threadIdx.x, lane = t & 63, w = t >> 6, g = lane >> 4, l15 = lane & 15;
  const int wm = w >> 1, wn = w & 1;
  const int nb = blockIdx.x * 128 + wn * 64, mb = blockIdx.y * 128 + wm * 64;
  const float* bias = biasq + (1 + kv) * 1024;
  const float* sE = sEF + kv * 256;
  if (!kv) {
    unsigned short* C = Kp + b * 262144;
#pragma unroll
    for (int nt = 0; nt < 4; ++nt) {
      const int n = nb + nt * 16 + l15;
      const float bn_ = bias[n];
#pragma unroll
      for (int mt = 0; mt < 4; ++mt) {
        const int m0 = mb + mt * 16 + g * 4;
        const f32x4 v = acc[mt][nt];
#pragma unroll
        for (int r = 0; r < 4; ++r) C[(m0 + r) * 1024 + n] = f2bf(v[r] + sE[m0 + r] * bn_);
      }
    }
  } else {
    unsigned short* C = VpT + b * 262144;
#pragma unroll
    for (int nt = 0; nt < 4; ++nt) {
      const int n = nb + nt * 16 + l15;
      const float bn_ = bias[n];
#pragma unroll
      for (int mt = 0; mt < 4; ++mt) {
        const int m0 = mb + mt * 16 + g * 4;
        const f32x4 v = acc[mt][nt];
        u16x4 pk;
#pragma unroll
        for (int r = 0; r < 4; ++r) pk[r] = f2bf(v[r] + sE[m0 + r] * bn_);
        *(u16x4*)(C + (n << 8) + m0) = pk;
      }
    }
  }
}

// ---------------------------------------------------------------------------
// Persistent-KV attention (unchanged).
// ---------------------------------------------------------------------------
__global__ __launch_bounds__(512, 2) void k_attn(const unsigned short* __restrict__ Qb,
                                                 const unsigned short* __restrict__ Kp,
                                                 const unsigned short* __restrict__ VpT,
                                                 unsigned short* __restrict__ AO) {
  __shared__ __align__(16) char lds[131072];
  char* K0 = lds;
  char* V0 = lds + 32768;
  char* Qd = lds + 65536;
  char* Pb = lds + 98304;
  const int t = threadIdx.x, lane = t & 63, w = t >> 6, g = lane >> 4, l15 = lane & 15;
  const int sh = blockIdx.x, h = blockIdx.y, b = blockIdx.z;
  const int s0 = sh * 2048;
  const unsigned short* Qg = Qb + (size_t)(b * 4096 + s0) * 1024 + h * 64;
  const unsigned short* Kg = Kp + b * 262144 + h * 64;
  const unsigned short* Vg = VpT + b * 262144 + (h * 64) * 256;

#pragma unroll
  for (int i = 0; i < 4; ++i) {
    const int c = i * 512 + t, row = c >> 3, slr = c & 7;
    gll16(Kg + row * 1024 + ((slr ^ (row & 7)) << 3), K0 + ((i * 512 + w * 64) << 4));
  }
#pragma unroll
  for (int i = 0; i < 4; ++i) {
    const int c = i * 512 + t, row = c >> 5, slr = c & 31;
    gll16(Vg + row * 256 + ((slr ^ (row & 7)) << 3), V0 + ((i * 512 + w * 64) << 4));
  }
#pragma unroll
  for (int i = 0; i < 2; ++i) {
    const int c = i * 512 + t, row = c >> 3, slr = c & 7;
    gll16(Qg + row * 1024 + ((slr ^ (row & 7)) << 3), Qd + ((i * 512 + w * 64) << 4));
  }
  __syncthreads();

  char* const PwRow = Pb + (w << 12) + l15 * 256;
  const int wOffP = (g * 8 + l15 * 16) & 255;
  const int qrow = w * 16 + l15;
  const int qsw0 = (g ^ (qrow & 7)) << 4;
  const int qsw1 = ((4 + g) ^ (qrow & 7)) << 4;

  for (int st = 0; st < 16; ++st) {
    char* qb = Qd + ((st & 1) << 14);
    const s16x8 aq0 = *(const s16x8*)(qb + qrow * 128 + qsw0);
    const s16x8 aq1 = *(const s16x8*)(qb + qrow * 128 + qsw1);
    if (st < 15) {
      const unsigned short* Qn = Qg + (size_t)(st + 1) * 131072;
      char* qn = Qd + (((st + 1) & 1) << 14);
#pragma unroll
      for (int i = 0; i < 2; ++i) {
        const int c = i * 512 + t, row = c >> 3, slr = c & 7;
        gll16(Qn + row * 1024 + ((slr ^ (row & 7)) << 3), qn + ((i * 512 + w * 64) << 4));
      }
    }

    f32x4 sc[16];
#pragma unroll
    for (int nt = 0; nt < 16; ++nt) sc[nt] = f32x4{0.f, 0.f, 0.f, 0.f};
#pragma unroll
    for (int nt = 0; nt < 16; ++nt) {
      const int row = nt * 16 + l15;
      const s16x8 b0 = *(const s16x8*)(K0 + row * 128 + ((g ^ (row & 7)) << 4));
      const s16x8 b1 = *(const s16x8*)(K0 + row * 128 + (((4 + g) ^ (row & 7)) << 4));
      sc[nt] = MFMA16(b0, aq0, sc[nt]);
      sc[nt] = MFMA16(b1, aq1, sc[nt]);
    }

    float sm_ = 0.f;
    f32x4 ov[4];
#pragma unroll
    for (int nt = 0; nt < 4; ++nt) ov[nt] = f32x4{0.f, 0.f, 0.f, 0.f};

#pragma unroll
    for (int half = 0; half < 2; ++half) {
#pragma unroll
      for (int nt2 = 0; nt2 < 8; ++nt2) {
        const f32x4 s4 = sc[half * 8 + nt2];
        const float p0 = __builtin_amdgcn_exp2f(s4[0]);
        const float p1 = __builtin_amdgcn_exp2f(s4[1]);
        const float p2 = __builtin_amdgcn_exp2f(s4[2]);
        const float p3 = __builtin_amdgcn_exp2f(s4[3]);
        sm_ += (p0 + p1) + (p2 + p3);
        u16x4 pk;
        pk[0] = f2bf(p0);
        pk[1] = f2bf(p1);
        pk[2] = f2bf(p2);
        pk[3] = f2bf(p3);
        *(u16x4*)(PwRow + ((nt2 * 32 + wOffP) & 255)) = pk;
      }
      FENCE();
#pragma unroll
      for (int kk = 0; kk < 4; ++kk) {
        const int slh = ((kk * 4 + g + l15) & 15) << 4;
        const s16x8 ap = *(const s16x8*)(PwRow + slh);
#pragma unroll
        for (int nt = 0; nt < 4; ++nt) {
          const int rv = nt * 16 + l15;
          const int slot = half * 16 + (kk << 2) + g;
          const s16x8 bv = *(const s16x8*)(V0 + rv * 512 + ((slot ^ (rv & 7)) << 4));
          ov[nt] = MFMA16(ap, bv, ov[nt]);
        }
      }
      FENCE();
    }
    sm_ += __shfl_xor(sm_, 16);
    sm_ += __shfl_xor(sm_, 32);
    const float inv = 1.f / sm_;
    float invr[4];
#pragma unroll
    for (int r = 0; r < 4; ++r) invr[r] = __shfl(inv, (g << 2) + r);

    unsigned short* Ao = AO + (size_t)(b * 4096 + s0 + st * 128 + w * 16) * 1024 + h * 64;
#pragma unroll
    for (int nt = 0; nt < 4; ++nt) {
#pragma unroll
      for (int r = 0; r < 4; ++r) {
        Ao[(g * 4 + r) * 1024 + nt * 16 + l15] = f2bf(ov[nt][r] * invr[r]);
      }
    }
    __syncthreads();
  }
}

// ---------------------------------------------------------------------------
// Transposing convert (exact r11-measured-best: 256 threads, 256x64 tile,
// 36KB LDS, 0 conflicts): xb[s][d] = bf16(x), xbT[b][d][s].
// ---------------------------------------------------------------------------
__global__ __launch_bounds__(256) void k_cvt_xt(const float* __restrict__ x,
                                                unsigned short* __restrict__ xb,
                                                unsigned short* __restrict__ xbT) {
  __shared__ unsigned short tl[256 * 72];
  const int t = threadIdx.x;
  const int stile = blockIdx.x >> 4, dt = blockIdx.x & 15;  // 128 s-tiles, 16 d-tiles
  const int s0 = stile * 256, d0 = dt * 64;
  const int q = t >> 4, l15 = t & 15;

#pragma unroll
  for (int p = 0; p < 16; ++p) {
    const int row = p * 16 + q;
    const float4 v = *(const float4*)(x + (size_t)(s0 + row) * 1024 + d0 + l15 * 4);
    u16x4 o;
    o[0] = f2bf(v.x);
    o[1] = f2bf(v.y);
    o[2] = f2bf(v.z);
    o[3] = f2bf(v.w);
    *(u16x4*)(xb + (size_t)(s0 + row) * 1024 + d0 + l15 * 4) = o;
    *(u16x4*)(tl + row * 72 + ((l15 ^ p) << 2)) = o;  // s>>4 == p
  }
  __syncthreads();

  u16x4 in[16];
#pragma unroll
  for (int i = 0; i < 16; ++i) {
    const int s = l15 * 16 + i;  // s>>4 == l15
    in[i] = *(const u16x4*)(tl + s * 72 + ((q ^ l15) << 2));
  }
  const int b = s0 >> 12, sb = s0 & 4095;
#pragma unroll
  for (int j = 0; j < 4; ++j) {
    u16x8 o0, o1;
#pragma unroll
    for (int i = 0; i < 8; ++i) {
      o0[i] = in[i][j];
      o1[i] = in[8 + i][j];
    }
    unsigned short* dst = xbT + (size_t)b * 4194304 + (size_t)(d0 + q * 4 + j) * 4096 + sb + l15 * 16;
    *(u16x8*)dst = o0;
    *(u16x8*)(dst + 8) = o1;
  }
}

// ---------------------------------------------------------------------------
// Prep: tiled LDS transposes (r13-proven) + bias pack + full E/F column sums.
// Blocks: [0,256) W tiles; [256,384) E/F tiles; [384,396) bias; [396,398) colsum.
// ---------------------------------------------------------------------------
__global__ __launch_bounds__(256) void k_prep(const float* __restrict__ Wq, const float* __restrict__ Wk,
                                              const float* __restrict__ Wv, const float* __restrict__ Wo,
                                              const float* __restrict__ E, const float* __restrict__ Fp,
                                              const float* __restrict__ bq, const float* __restrict__ bk,
                                              const float* __restrict__ bv,
                                              unsigned short* __restrict__ Wqkvt, unsigned short* __restrict__ Wot,
                                              unsigned short* __restrict__ Et, unsigned short* __restrict__ Ft,
                                              float* __restrict__ biasq, float* __restrict__ sEF) {
  __shared__ unsigned short tl[256 * 72];
  const int bid = blockIdx.x, t = threadIdx.x;
  if (bid >= 384) {
    if (bid < 396) {  // bias pack
      const int j = (bid - 384) * 256 + t;
      biasq[j] = (j < 1024) ? bq[j] : (j < 2048 ? bk[j - 1024] : bv[j - 2048]);
    } else {  // full column sum: one block per ef, thread k sums 4096 rows
      const int ef = bid - 396, k = t;
      const float* M = ef ? Fp : E;
      float s = 0.f;
#pragma unroll 4
      for (int i = 0; i < 4096; ++i) s += M[(size_t)i * 256 + k];
      sEF[ef * 256 + k] = s;
    }
    return;
  }
  const float* src;
  unsigned short* dst;
  int srcld, dstld, s0, d0;
  if (bid < 256) {  // W transposes: [1024(k)][1024(n)] -> [n][k]
    const int m = bid >> 6, tile = bid & 63;
    src = (m == 0) ? Wq : (m == 1) ? Wk : (m == 2) ? Wv : Wo;
    dst = (m < 3) ? (Wqkvt + m * 1048576) : Wot;
    srcld = 1024;
    dstld = 1024;
    s0 = (tile >> 4) * 256;  // k
    d0 = (tile & 15) * 64;   // n
  } else {  // E/F transposes: [4096(s)][256(kp)] -> [kp][s]
    const int j = bid - 256, ef = j >> 6, tile = j & 63;
    src = ef ? Fp : E;
    dst = ef ? Ft : Et;
    srcld = 256;
    dstld = 4096;
    s0 = (tile >> 2) * 256;  // s
    d0 = (tile & 3) * 64;    // kp
  }
  const int q = t >> 4, l15 = t & 15;
#pragma unroll
  for (int p = 0; p < 16; ++p) {
    const int row = p * 16 + q;
    const float4 v = *(const float4*)(src + (size_t)(s0 + row) * srcld + d0 + l15 * 4);
    u16x4 o;
    o[0] = f2bf(v.x);
    o[1] = f2bf(v.y);
    o[2] = f2bf(v.z);
    o[3] = f2bf(v.w);
    *(u16x4*)(tl + row * 72 + ((l15 ^ p) << 2)) = o;
  }
  __syncthreads();
  u16x4 in[16];
#pragma unroll
  for (int i = 0; i < 16; ++i) {
    const int s = l15 * 16 + i;
    in[i] = *(const u16x4*)(tl + s * 72 + ((q ^ l15) << 2));
  }
#pragma unroll
  for (int j = 0; j < 4; ++j) {
    u16x8 o0, o1;
#pragma unroll
    for (int i = 0; i < 8; ++i) {
      o0[i] = in[i][j];
      o1[i] = in[8 + i][j];
    }
    unsigned short* dp = dst + (size_t)(d0 + q * 4 + j) * dstld + s0 + l15 * 16;
    *(u16x8*)dp = o0;
    *(u16x8*)(dp + 8) = o1;
  }
}

// ---------------------------------------------------------------------------
extern "C" void kernel_launch(void* const* d_in, const int* in_sizes, int n_in,
                              void* d_out, int out_size, void* d_ws, size_t ws_size,
                              hipStream_t stream) {
  const float* x = (const float*)d_in[0];
  const float* Wq = (const float*)d_in[1];
  const float* bq = (const float*)d_in[2];
  const float* Wk = (const float*)d_in[3];
  const float* bk = (const float*)d_in[4];
  const float* Wv = (const float*)d_in[5];
  const float* bv = (const float*)d_in[6];
  const float* Wo = (const float*)d_in[7];
  const float* bo = (const float*)d_in[8];
  const float* E = (const float*)d_in[9];
  const float* Fp = (const float*)d_in[10];

  char* ws = (char*)d_ws;
  size_t off = 0;
  auto alloc = [&](size_t bytes) {
    char* p = ws + off;
    off += (bytes + 255) & ~(size_t)255;
    return p;
  };
  unsigned short* xb = (unsigned short*)alloc(33554432ull * 2);
  unsigned short* xbT = (unsigned short*)alloc(33554432ull * 2);
  unsigned short* Qb = (unsigned short*)alloc(33554432ull * 2);
  unsigned short* Wqkvt = (unsigned short*)alloc(3145728ull * 2);
  unsigned short* Wot = (unsigned short*)alloc(1048576ull * 2);
  unsigned short* Et = (unsigned short*)alloc(1048576ull * 2);
  unsigned short* Ft = (unsigned short*)alloc(1048576ull * 2);
  unsigned short* xEF = (unsigned short*)alloc(4194304ull * 2);
  unsigned short* Kp = (unsigned short*)alloc(2097152ull * 2);
  unsigned short* VpT = (unsigned short*)alloc(2097152ull * 2);
  float* pxef = (float*)alloc(16777216ull * 4);
  float* biasq = (float*)alloc(3072 * 4);
  float* sEF = (float*)alloc(512 * 4);
  (void)in_sizes; (void)n_in; (void)out_size; (void)ws_size;

  k_cvt_xt<<<2048, 256, 0, stream>>>(x, xb, xbT);
  k_prep<<<398, 256, 0, stream>>>(Wq, Wk, Wv, Wo, E, Fp, bq, bk, bv,
                                  Wqkvt, Wot, Et, Ft, biasq, sEF);
  k_gemm_q<<<dim3(4, 128), 512, 0, stream>>>(xb, Wqkvt, biasq, Qb);
  k_gemm_xef<<<dim3(4, 1, 64), 512, 0, stream>>>(Et, Ft, xbT, pxef);
  k_xef_red<<<4096, 256, 0, stream>>>(pxef, xEF);
  k_kpvp2<<<dim3(8, 2, 16), 256, 0, stream>>>(xEF, Wqkvt, biasq, sEF, Kp, VpT);
  k_attn<<<dim3(2, 16, 8), 512, 0, stream>>>(Qb, Kp, VpT, xb);
  k_gemm_out<<<dim3(4, 128), 512, 0, stream>>>(xb, Wot, bo, (float*)d_out);
}

// Round 16
// 386.118 us; speedup vs baseline: 1.5584x; 1.5584x over previous
//
#include <hip/hip_runtime.h>

#define AS1 __attribute__((address_space(1)))
#define AS3 __attribute__((address_space(3)))

typedef __attribute__((ext_vector_type(8))) short s16x8;
typedef __attribute__((ext_vector_type(4))) float f32x4;
typedef __attribute__((ext_vector_type(4))) unsigned short u16x4;
typedef __attribute__((ext_vector_type(8))) unsigned short u16x8;

#define MFMA16(a, b, c) __builtin_amdgcn_mfma_f32_16x16x32_bf16(a, b, c, 0, 0, 0)

static __device__ __forceinline__ unsigned short f2bf(float f) {
  unsigned u = __builtin_bit_cast(unsigned, f);
  u += 0x7fffu + ((u >> 16) & 1u);
  return (unsigned short)(u >> 16);
}

static __device__ __forceinline__ void gll16(const unsigned short* g, char* l) {
  __builtin_amdgcn_global_load_lds((const AS1 void*)g, (AS3 void*)l, 16, 0, 0);
}

#define BAR() asm volatile("s_barrier" ::: "memory")
#define WAITV(N) asm volatile("s_waitcnt vmcnt(" #N ")" ::: "memory")
#define FENCE() asm volatile("" ::: "memory")

// ===========================================================================
// 256x256 8-phase pipelined GEMM core (C = A[M,K] @ B[N,K]^T), bf16, f32 acc.
// (r10-proven schedule)
// ===========================================================================
__device__ __forceinline__ void gemm256_pipe(const unsigned short* __restrict__ A0, int lda,
                                             const unsigned short* __restrict__ B0, int ldb,
                                             int NT2, char* lds, f32x4 (&acc)[8][4]) {
  const int t = threadIdx.x;
  const int lane = t & 63, w = t >> 6, g = lane >> 4, l15 = lane & 15;
  const int wm = w >> 2, wn = w & 3;
  char* const A_lds[2] = {lds, lds + 65536};
  char* const B_lds[2] = {lds + 32768, lds + 98304};
  s16x8 af[2][4], bfr[2][4];

  const int rl = t >> 3, sl = t & 7;
  const unsigned short* aB = A0 + (size_t)rl * lda + ((sl ^ (rl & 7)) << 3);
  const unsigned short* bB = B0 + (size_t)rl * ldb + ((sl ^ (rl & 7)) << 3);
  const int woff = w << 10;

  char* pA[2][2];
  char* pB[2][2];
#pragma unroll
  for (int b = 0; b < 2; ++b)
#pragma unroll
    for (int kk = 0; kk < 2; ++kk) {
      pA[b][kk] = lds + b * 65536 + (wm * 64 + l15) * 128 + (((kk * 4 + g) ^ (l15 & 7)) << 4);
      pB[b][kk] = lds + 32768 + b * 65536 + (wn * 32 + l15) * 128 + (((kk * 4 + g) ^ (l15 & 7)) << 4);
    }

#define STGA(BUF, H, PTR)                                                                \
  do {                                                                                   \
    gll16((PTR) + (size_t)((H)*128) * lda, A_lds[BUF] + woff + (H)*16384);               \
    gll16((PTR) + (size_t)((H)*128 + 64) * lda, A_lds[BUF] + woff + (H)*16384 + 8192);   \
  } while (0)
#define STGB(BUF, H, PTR)                                                                \
  do {                                                                                   \
    gll16((PTR) + (size_t)((H)*128) * ldb, B_lds[BUF] + woff + (H)*16384);               \
    gll16((PTR) + (size_t)((H)*128 + 64) * ldb, B_lds[BUF] + woff + (H)*16384 + 8192);   \
  } while (0)

#define LDAQ(BUF, QH)                                                                    \
  do {                                                                                   \
    _Pragma("unroll") for (int mi = 0; mi < 4; ++mi)                                     \
        _Pragma("unroll") for (int kk = 0; kk < 2; ++kk)                                 \
            af[kk][mi] = *(const s16x8*)(pA[BUF][kk] + (QH)*16384 + mi * 2048);          \
  } while (0)
#define LDBP(BUF, NH)                                                                    \
  do {                                                                                   \
    _Pragma("unroll") for (int ni = 0; ni < 2; ++ni)                                     \
        _Pragma("unroll") for (int kk = 0; kk < 2; ++kk)                                 \
            bfr[kk][(NH)*2 + ni] =                                                       \
                *(const s16x8*)(pB[BUF][kk] + (NH)*16384 + ni * 2048);                   \
  } while (0)
#define MQUAD(QH, NH)                                                                    \
  do {                                                                                   \
    __builtin_amdgcn_s_setprio(1);                                                       \
    _Pragma("unroll") for (int kk = 0; kk < 2; ++kk)                                     \
        _Pragma("unroll") for (int mi = 0; mi < 4; ++mi)                                 \
            _Pragma("unroll") for (int ni = 0; ni < 2; ++ni)                             \
                acc[(QH)*4 + mi][(NH)*2 + ni] =                                          \
        MFMA16(af[kk][mi], bfr[kk][(NH)*2 + ni], acc[(QH)*4 + mi][(NH)*2 + ni]);         \
    __builtin_amdgcn_s_setprio(0);                                                       \
  } while (0)

  STGA(0, 0, aB);
  STGB(0, 0, bB);
  STGB(0, 1, bB);
  STGA(0, 1, aB);
  STGA(1, 0, aB + 64);
  STGB(1, 0, bB + 64);
  STGB(1, 1, bB + 64);
  STGA(1, 1, aB + 64);
  WAITV(8);
  BAR();

  for (int it = 0; it < NT2; ++it) {
    const bool pf = (it + 1 < NT2);
    const unsigned short* aN = aB + it * 128 + 128;
    const unsigned short* bN = bB + it * 128 + 128;
    LDAQ(0, 0);
    LDBP(0, 0);
    MQUAD(0, 0);
    BAR();
    LDBP(0, 1);
    if (pf) { STGA(0, 0, aN); STGB(0, 0, bN); }
    MQUAD(0, 1);
    BAR();
    LDAQ(0, 1);
    if (pf) STGB(0, 1, bN);
    MQUAD(1, 0);
    BAR();
    if (pf) STGA(0, 1, aN);
    MQUAD(1, 1);
    if (pf) WAITV(8);
    else WAITV(0);
    BAR();
    LDAQ(1, 0);
    LDBP(1, 0);
    MQUAD(0, 0);
    BAR();
    LDBP(1, 1);
    if (pf) { STGA(1, 0, aN + 64); STGB(1, 0, bN + 64); }
    MQUAD(0, 1);
    BAR();
    LDAQ(1, 1);
    if (pf) STGB(1, 1, bN + 64);
    MQUAD(1, 0);
    BAR();
    if (pf) STGA(1, 1, aN + 64);
    MQUAD(1, 1);
    if (pf) WAITV(8);
    BAR();
  }
#undef STGA
#undef STGB
#undef LDAQ
#undef LDBP
#undef MQUAD
}

// ---------------------------------------------------------------------------
// Q projection (8-phase 256^2): Qb = (x @ Wq^T + bq) * (log2e/8), bf16 out.
// ---------------------------------------------------------------------------
__global__ __launch_bounds__(512, 2) void k_gemm_q(const unsigned short* __restrict__ xb,
                                                   const unsigned short* __restrict__ Wqt,
                                                   const float* __restrict__ biasq,
                                                   unsigned short* __restrict__ Qb) {
  __shared__ __align__(16) char lds[131072];
  f32x4 acc[8][4];
#pragma unroll
  for (int i = 0; i < 8; ++i)
#pragma unroll
    for (int j = 0; j < 4; ++j) acc[i][j] = f32x4{0.f, 0.f, 0.f, 0.f};
  int bid = blockIdx.y * 4 + blockIdx.x;  // nwg = 512
  bid = (bid & 7) * 64 + (bid >> 3);
  const int bn = bid & 3, bm = bid >> 2;
  gemm256_pipe(xb + (size_t)bm * 256 * 1024, 1024, Wqt + (size_t)bn * 256 * 1024, 1024, 8, lds, acc);

  const int t = threadIdx.x, lane = t & 63, w = t >> 6, g = lane >> 4, l15 = lane & 15;
  const int wm = w >> 2, wn = w & 3;
  const float QSC = 0.1803368801111204f;  // log2e / 8
#pragma unroll
  for (int nf = 0; nf < 4; ++nf) {
    const int n = bn * 256 + (nf >> 1) * 128 + wn * 32 + (nf & 1) * 16 + l15;
    const float bias = biasq[n];
#pragma unroll
    for (int mq = 0; mq < 8; ++mq) {
      const int m0 = bm * 256 + (mq >> 2) * 128 + wm * 64 + (mq & 3) * 16 + g * 4;
      const f32x4 v = acc[mq][nf];
#pragma unroll
      for (int r = 0; r < 4; ++r) Qb[(size_t)(m0 + r) * 1024 + n] = f2bf((v[r] + bias) * QSC);
    }
  }
}

// ---------------------------------------------------------------------------
// Output projection (8-phase 256^2): f32 out = AO_bf16 @ Wo^T + bo
// ---------------------------------------------------------------------------
__global__ __launch_bounds__(512, 2) void k_gemm_out(const unsigned short* __restrict__ AO,
                                                     const unsigned short* __restrict__ Wot,
                                                     const float* __restrict__ bo,
                                                     float* __restrict__ out) {
  __shared__ __align__(16) char lds[131072];
  f32x4 acc[8][4];
#pragma unroll
  for (int i = 0; i < 8; ++i)
#pragma unroll
    for (int j = 0; j < 4; ++j) acc[i][j] = f32x4{0.f, 0.f, 0.f, 0.f};
  int bid = blockIdx.y * 4 + blockIdx.x;  // nwg = 512
  bid = (bid & 7) * 64 + (bid >> 3);
  const int bn = bid & 3, bm = bid >> 2;
  gemm256_pipe(AO + (size_t)bm * 256 * 1024, 1024, Wot + (size_t)bn * 256 * 1024, 1024, 8, lds, acc);

  const int t = threadIdx.x, lane = t & 63, w = t >> 6, g = lane >> 4, l15 = lane & 15;
  const int wm = w >> 2, wn = w & 3;
#pragma unroll
  for (int nf = 0; nf < 4; ++nf) {
    const int n = bn * 256 + (nf >> 1) * 128 + wn * 32 + (nf & 1) * 16 + l15;
    const float bias = bo[n];
#pragma unroll
    for (int mq = 0; mq < 8; ++mq) {
      const int m0 = bm * 256 + (mq >> 2) * 128 + wm * 64 + (mq & 3) * 16 + g * 4;
      const f32x4 v = acc[mq][nf];
#pragma unroll
      for (int r = 0; r < 4; ++r) out[(size_t)(m0 + r) * 1024 + n] = v[r] + bias;
    }
  }
}

// ---------------------------------------------------------------------------
// xE/xF split-K on the 8-phase 256^2 core. Grid (4 n-tiles, 1, 64 z) = 256
// blocks = 1/CU. z = ks*16 + (b*2+ef); K-chunk 1024 (NT2=8); f32 partials.
// ---------------------------------------------------------------------------
__global__ __launch_bounds__(512, 2) void k_gemm_xef(const unsigned short* __restrict__ Et,
                                                     const unsigned short* __restrict__ Ft,
                                                     const unsigned short* __restrict__ xbT,
                                                     float* __restrict__ pxef) {
  __shared__ __align__(16) char lds[131072];
  f32x4 acc[8][4];
#pragma unroll
  for (int i = 0; i < 8; ++i)
#pragma unroll
    for (int j = 0; j < 4; ++j) acc[i][j] = f32x4{0.f, 0.f, 0.f, 0.f};
  const int z = blockIdx.z;
  const int ks = z >> 4, pair = z & 15, b = pair >> 1, ef = pair & 1;
  const unsigned short* Ab = (ef ? Ft : Et) + ks * 1024;
  const unsigned short* Bb = xbT + (size_t)b * 4194304 + (size_t)blockIdx.x * 256 * 4096 + ks * 1024;
  gemm256_pipe(Ab, 4096, Bb, 4096, 8, lds, acc);

  const int t = threadIdx.x, lane = t & 63, w = t >> 6, g = lane >> 4, l15 = lane & 15;
  const int wm = w >> 2, wn = w & 3;
  float* C = pxef + (size_t)z * 262144;
#pragma unroll
  for (int nf = 0; nf < 4; ++nf) {
    const int n = blockIdx.x * 256 + (nf >> 1) * 128 + wn * 32 + (nf & 1) * 16 + l15;
#pragma unroll
    for (int mq = 0; mq < 8; ++mq) {
      const int m0 = (mq >> 2) * 128 + wm * 64 + (mq & 3) * 16 + g * 4;
      const f32x4 v = acc[mq][nf];
#pragma unroll
      for (int r = 0; r < 4; ++r) C[(size_t)(m0 + r) * 1024 + n] = v[r];
    }
  }
}

// ---------------------------------------------------------------------------
// Split-K reduce: xEF[j] = bf16(sum_ks pxef[ks][j]), vectorized x4.
// ---------------------------------------------------------------------------
__global__ __launch_bounds__(256) void k_xef_red(const float* __restrict__ pxef,
                                                 unsigned short* __restrict__ xEF) {
  const int j = (blockIdx.x * 256 + threadIdx.x) * 4;
  f32x4 s = *(const f32x4*)(pxef + j);
#pragma unroll
  for (int ks = 1; ks < 4; ++ks) {
    const f32x4 p = *(const f32x4*)(pxef + (size_t)ks * 4194304 + j);
#pragma unroll
    for (int r = 0; r < 4; ++r) s[r] += p[r];
  }
  u16x4 o;
#pragma unroll
  for (int r = 0; r < 4; ++r) o[r] = f2bf(s[r]);
  *(u16x4*)(xEF + j) = o;
}

// ===========================================================================
// 128x128 2-barrier GEMM core (kpvp2 only)
// ===========================================================================
__device__ __forceinline__ void gemm_tile(const unsigned short* __restrict__ Ab, int lda,
                                          const unsigned short* __restrict__ Bb, int ldb,
                                          int Kc, char* lds, f32x4 (&acc)[4][4]) {
  const int t = threadIdx.x;
  const int lane = t & 63, w = t >> 6, g = lane >> 4, l15 = lane & 15;
  const int wm = w >> 1, wn = w & 1;
  char* As = lds;
  char* Bs = lds + 16384;
  for (int ks = 0; ks < Kc; ks += 64) {
    __syncthreads();
#pragma unroll
    for (int i = 0; i < 4; ++i) {
      const int c = i * 256 + t, row = c >> 3, sl = c & 7;
      const int col = ks + ((sl ^ (row & 7)) << 3);
      const int ubase = (i * 256 + w * 64) << 4;
      gll16(Ab + (size_t)row * lda + col, As + ubase);
      gll16(Bb + (size_t)row * ldb + col, Bs + ubase);
    }
    __syncthreads();
    s16x8 af[2][4], bfr[2][4];
#pragma unroll
    for (int kk = 0; kk < 2; ++kk)
#pragma unroll
      for (int x4 = 0; x4 < 4; ++x4) {
        const int ra = wm * 64 + x4 * 16 + l15;
        const int rb = wn * 64 + x4 * 16 + l15;
        af[kk][x4] = *(const s16x8*)(As + ra * 128 + ((((kk << 2) + g) ^ (ra & 7)) << 4));
        bfr[kk][x4] = *(const s16x8*)(Bs + rb * 128 + ((((kk << 2) + g) ^ (rb & 7)) << 4));
      }
#pragma unroll
    for (int kk = 0; kk < 2; ++kk)
#pragma unroll
      for (int mt = 0; mt < 4; ++mt)
#pragma unroll
        for (int nt = 0; nt < 4; ++nt)
          acc[mt][nt] = MFMA16(af[kk][mt], bfr[kk][nt], acc[mt][nt]);
  }
}

// ---------------------------------------------------------------------------
// Kp/Vp: per (b, kv): C[256,1024] = xEF_b,kv @ W{k,v}t^T + sEF[kp]*b{k,v}[d].
// ---------------------------------------------------------------------------
__global__ __launch_bounds__(256) void k_kpvp2(const unsigned short* __restrict__ xEF,
                                               const unsigned short* __restrict__ Wqkvt,
                                               const float* __restrict__ biasq,
                                               const float* __restrict__ sEF,
                                               unsigned short* __restrict__ Kp,
                                               unsigned short* __restrict__ VpT) {
  __shared__ __align__(16) char lds[32768];
  f32x4 acc[4][4];
#pragma unroll
  for (int i = 0; i < 4; ++i)
#pragma unroll
    for (int j = 0; j < 4; ++j) acc[i][j] = f32x4{0.f, 0.f, 0.f, 0.f};
  const int b = blockIdx.z >> 1, kv = blockIdx.z & 1;
  const unsigned short* Ab = xEF + (size_t)(b * 2 + kv) * 262144 + blockIdx.y * 128 * 1024;
  const unsigned short* Bb = Wqkvt + (size_t)(1 + kv) * 1048576 + blockIdx.x * 128 * 1024;
  gemm_tile(Ab, 1024, Bb, 1024, 1024, lds, acc);

  const int t = threadIdx.x, lane = t & 63, w = t >> 6, g = lane >> 4, l15 = lane & 15;
  const int wm = w >> 1, wn = w & 1;
  const int nb = blockIdx.x * 128 + wn * 64, mb = blockIdx.y * 128 + wm * 64;
  const float* bias = biasq + (1 + kv) * 1024;
  const float* sE = sEF + kv * 256;
  if (!kv) {
    unsigned short* C = Kp + b * 262144;
#pragma unroll
    for (int nt = 0; nt < 4; ++nt) {
      const int n = nb + nt * 16 + l15;
      const float bn_ = bias[n];
#pragma unroll
      for (int mt = 0; mt < 4; ++mt) {
        const int m0 = mb + mt * 16 + g * 4;
        const f32x4 v = acc[mt][nt];
#pragma unroll
        for (int r = 0; r < 4; ++r) C[(m0 + r) * 1024 + n] = f2bf(v[r] + sE[m0 + r] * bn_);
      }
    }
  } else {
    unsigned short* C = VpT + b * 262144;
#pragma unroll
    for (int nt = 0; nt < 4; ++nt) {
      const int n = nb + nt * 16 + l15;
      const float bn_ = bias[n];
#pragma unroll
      for (int mt = 0; mt < 4; ++mt) {
        const int m0 = mb + mt * 16 + g * 4;
        const f32x4 v = acc[mt][nt];
        u16x4 pk;
#pragma unroll
        for (int r = 0; r < 4; ++r) pk[r] = f2bf(v[r] + sE[m0 + r] * bn_);
        *(u16x4*)(C + (n << 8) + m0) = pk;
      }
    }
  }
}

// ---------------------------------------------------------------------------
// Persistent-KV attention (unchanged).
// ---------------------------------------------------------------------------
__global__ __launch_bounds__(512, 2) void k_attn(const unsigned short* __restrict__ Qb,
                                                 const unsigned short* __restrict__ Kp,
                                                 const unsigned short* __restrict__ VpT,
                                                 unsigned short* __restrict__ AO) {
  __shared__ __align__(16) char lds[131072];
  char* K0 = lds;
  char* V0 = lds + 32768;
  char* Qd = lds + 65536;
  char* Pb = lds + 98304;
  const int t = threadIdx.x, lane = t & 63, w = t >> 6, g = lane >> 4, l15 = lane & 15;
  const int sh = blockIdx.x, h = blockIdx.y, b = blockIdx.z;
  const int s0 = sh * 2048;
  const unsigned short* Qg = Qb + (size_t)(b * 4096 + s0) * 1024 + h * 64;
  const unsigned short* Kg = Kp + b * 262144 + h * 64;
  const unsigned short* Vg = VpT + b * 262144 + (h * 64) * 256;

#pragma unroll
  for (int i = 0; i < 4; ++i) {
    const int c = i * 512 + t, row = c >> 3, slr = c & 7;
    gll16(Kg + row * 1024 + ((slr ^ (row & 7)) << 3), K0 + ((i * 512 + w * 64) << 4));
  }
#pragma unroll
  for (int i = 0; i < 4; ++i) {
    const int c = i * 512 + t, row = c >> 5, slr = c & 31;
    gll16(Vg + row * 256 + ((slr ^ (row & 7)) << 3), V0 + ((i * 512 + w * 64) << 4));
  }
#pragma unroll
  for (int i = 0; i < 2; ++i) {
    const int c = i * 512 + t, row = c >> 3, slr = c & 7;
    gll16(Qg + row * 1024 + ((slr ^ (row & 7)) << 3), Qd + ((i * 512 + w * 64) << 4));
  }
  __syncthreads();

  char* const PwRow = Pb + (w << 12) + l15 * 256;
  const int wOffP = (g * 8 + l15 * 16) & 255;
  const int qrow = w * 16 + l15;
  const int qsw0 = (g ^ (qrow & 7)) << 4;
  const int qsw1 = ((4 + g) ^ (qrow & 7)) << 4;

  for (int st = 0; st < 16; ++st) {
    char* qb = Qd + ((st & 1) << 14);
    const s16x8 aq0 = *(const s16x8*)(qb + qrow * 128 + qsw0);
    const s16x8 aq1 = *(const s16x8*)(qb + qrow * 128 + qsw1);
    if (st < 15) {
      const unsigned short* Qn = Qg + (size_t)(st + 1) * 131072;
      char* qn = Qd + (((st + 1) & 1) << 14);
#pragma unroll
      for (int i = 0; i < 2; ++i) {
        const int c = i * 512 + t, row = c >> 3, slr = c & 7;
        gll16(Qn + row * 1024 + ((slr ^ (row & 7)) << 3), qn + ((i * 512 + w * 64) << 4));
      }
    }

    f32x4 sc[16];
#pragma unroll
    for (int nt = 0; nt < 16; ++nt) sc[nt] = f32x4{0.f, 0.f, 0.f, 0.f};
#pragma unroll
    for (int nt = 0; nt < 16; ++nt) {
      const int row = nt * 16 + l15;
      const s16x8 b0 = *(const s16x8*)(K0 + row * 128 + ((g ^ (row & 7)) << 4));
      const s16x8 b1 = *(const s16x8*)(K0 + row * 128 + (((4 + g) ^ (row & 7)) << 4));
      sc[nt] = MFMA16(b0, aq0, sc[nt]);
      sc[nt] = MFMA16(b1, aq1, sc[nt]);
    }

    float sm_ = 0.f;
    f32x4 ov[4];
#pragma unroll
    for (int nt = 0; nt < 4; ++nt) ov[nt] = f32x4{0.f, 0.f, 0.f, 0.f};

#pragma unroll
    for (int half = 0; half < 2; ++half) {
#pragma unroll
      for (int nt2 = 0; nt2 < 8; ++nt2) {
        const f32x4 s4 = sc[half * 8 + nt2];
        const float p0 = __builtin_amdgcn_exp2f(s4[0]);
        const float p1 = __builtin_amdgcn_exp2f(s4[1]);
        const float p2 = __builtin_amdgcn_exp2f(s4[2]);
        const float p3 = __builtin_amdgcn_exp2f(s4[3]);
        sm_ += (p0 + p1) + (p2 + p3);
        u16x4 pk;
        pk[0] = f2bf(p0);
        pk[1] = f2bf(p1);
        pk[2] = f2bf(p2);
        pk[3] = f2bf(p3);
        *(u16x4*)(PwRow + ((nt2 * 32 + wOffP) & 255)) = pk;
      }
      FENCE();
#pragma unroll
      for (int kk = 0; kk < 4; ++kk) {
        const int slh = ((kk * 4 + g + l15) & 15) << 4;
        const s16x8 ap = *(const s16x8*)(PwRow + slh);
#pragma unroll
        for (int nt = 0; nt < 4; ++nt) {
          const int rv = nt * 16 + l15;
          const int slot = half * 16 + (kk << 2) + g;
          const s16x8 bv = *(const s16x8*)(V0 + rv * 512 + ((slot ^ (rv & 7)) << 4));
          ov[nt] = MFMA16(ap, bv, ov[nt]);
        }
      }
      FENCE();
    }
    sm_ += __shfl_xor(sm_, 16);
    sm_ += __shfl_xor(sm_, 32);
    const float inv = 1.f / sm_;
    float invr[4];
#pragma unroll
    for (int r = 0; r < 4; ++r) invr[r] = __shfl(inv, (g << 2) + r);

    unsigned short* Ao = AO + (size_t)(b * 4096 + s0 + st * 128 + w * 16) * 1024 + h * 64;
#pragma unroll
    for (int nt = 0; nt < 4; ++nt) {
#pragma unroll
      for (int r = 0; r < 4; ++r) {
        Ao[(g * 4 + r) * 1024 + nt * 16 + l15] = f2bf(ov[nt][r] * invr[r]);
      }
    }
    __syncthreads();
  }
}

// ---------------------------------------------------------------------------
// Transposing convert (r11-measured-best): xb[s][d] = bf16(x), xbT[b][d][s].
// ---------------------------------------------------------------------------
__global__ __launch_bounds__(256) void k_cvt_xt(const float* __restrict__ x,
                                                unsigned short* __restrict__ xb,
                                                unsigned short* __restrict__ xbT) {
  __shared__ unsigned short tl[256 * 72];
  const int t = threadIdx.x;
  const int stile = blockIdx.x >> 4, dt = blockIdx.x & 15;
  const int s0 = stile * 256, d0 = dt * 64;
  const int q = t >> 4, l15 = t & 15;

#pragma unroll
  for (int p = 0; p < 16; ++p) {
    const int row = p * 16 + q;
    const float4 v = *(const float4*)(x + (size_t)(s0 + row) * 1024 + d0 + l15 * 4);
    u16x4 o;
    o[0] = f2bf(v.x);
    o[1] = f2bf(v.y);
    o[2] = f2bf(v.z);
    o[3] = f2bf(v.w);
    *(u16x4*)(xb + (size_t)(s0 + row) * 1024 + d0 + l15 * 4) = o;
    *(u16x4*)(tl + row * 72 + ((l15 ^ p) << 2)) = o;  // s>>4 == p
  }
  __syncthreads();

  u16x4 in[16];
#pragma unroll
  for (int i = 0; i < 16; ++i) {
    const int s = l15 * 16 + i;  // s>>4 == l15
    in[i] = *(const u16x4*)(tl + s * 72 + ((q ^ l15) << 2));
  }
  const int b = s0 >> 12, sb = s0 & 4095;
#pragma unroll
  for (int j = 0; j < 4; ++j) {
    u16x8 o0, o1;
#pragma unroll
    for (int i = 0; i < 8; ++i) {
      o0[i] = in[i][j];
      o1[i] = in[8 + i][j];
    }
    unsigned short* dst = xbT + (size_t)b * 4194304 + (size_t)(d0 + q * 4 + j) * 4096 + sb + l15 * 16;
    *(u16x8*)dst = o0;
    *(u16x8*)(dst + 8) = o1;
  }
}

// ---------------------------------------------------------------------------
// Column-sum stage 1 (r14-proven 32-block version)
// ---------------------------------------------------------------------------
__global__ __launch_bounds__(256) void k_colsum1(const float* __restrict__ E,
                                                 const float* __restrict__ Fp,
                                                 float* __restrict__ part) {
  const int sc = blockIdx.x, ef = blockIdx.y, k = threadIdx.x;
  const float* M = ef ? Fp : E;
  float s = 0.f;
#pragma unroll 4
  for (int i = 0; i < 256; ++i) s += M[(size_t)((sc << 8) + i) * 256 + k];
  part[(ef * 16 + sc) * 256 + k] = s;
}

// ---------------------------------------------------------------------------
// Prep: tiled LDS transposes (r13-proven) + bias pack + colsum stage 2.
// Blocks: [0,256) W tiles; [256,384) E/F tiles; [384,396) bias; [396,398) cs2.
// ---------------------------------------------------------------------------
__global__ __launch_bounds__(256) void k_prep(const float* __restrict__ Wq, const float* __restrict__ Wk,
                                              const float* __restrict__ Wv, const float* __restrict__ Wo,
                                              const float* __restrict__ E, const float* __restrict__ Fp,
                                              const float* __restrict__ bq, const float* __restrict__ bk,
                                              const float* __restrict__ bv,
                                              const float* __restrict__ part,
                                              unsigned short* __restrict__ Wqkvt, unsigned short* __restrict__ Wot,
                                              unsigned short* __restrict__ Et, unsigned short* __restrict__ Ft,
                                              float* __restrict__ biasq, float* __restrict__ sEF) {
  __shared__ unsigned short tl[256 * 72];
  const int bid = blockIdx.x, t = threadIdx.x;
  if (bid >= 384) {
    if (bid < 396) {  // bias pack
      const int j = (bid - 384) * 256 + t;
      biasq[j] = (j < 1024) ? bq[j] : (j < 2048 ? bk[j - 1024] : bv[j - 2048]);
    } else {  // colsum stage 2
      const int j = (bid - 396) * 256 + t;
      const int ef = j >> 8, k = j & 255;
      float s = 0.f;
#pragma unroll
      for (int c = 0; c < 16; ++c) s += part[(ef * 16 + c) * 256 + k];
      sEF[j] = s;
    }
    return;
  }
  const float* src;
  unsigned short* dst;
  int srcld, dstld, s0, d0;
  if (bid < 256) {  // W transposes: [1024(k)][1024(n)] -> [n][k]
    const int m = bid >> 6, tile = bid & 63;
    src = (m == 0) ? Wq : (m == 1) ? Wk : (m == 2) ? Wv : Wo;
    dst = (m < 3) ? (Wqkvt + m * 1048576) : Wot;
    srcld = 1024;
    dstld = 1024;
    s0 = (tile >> 4) * 256;  // k
    d0 = (tile & 15) * 64;   // n
  } else {  // E/F transposes: [4096(s)][256(kp)] -> [kp][s]
    const int j = bid - 256, ef = j >> 6, tile = j & 63;
    src = ef ? Fp : E;
    dst = ef ? Ft : Et;
    srcld = 256;
    dstld = 4096;
    s0 = (tile >> 2) * 256;  // s
    d0 = (tile & 3) * 64;    // kp
  }
  const int q = t >> 4, l15 = t & 15;
#pragma unroll
  for (int p = 0; p < 16; ++p) {
    const int row = p * 16 + q;
    const float4 v = *(const float4*)(src + (size_t)(s0 + row) * srcld + d0 + l15 * 4);
    u16x4 o;
    o[0] = f2bf(v.x);
    o[1] = f2bf(v.y);
    o[2] = f2bf(v.z);
    o[3] = f2bf(v.w);
    *(u16x4*)(tl + row * 72 + ((l15 ^ p) << 2)) = o;
  }
  __syncthreads();
  u16x4 in[16];
#pragma unroll
  for (int i = 0; i < 16; ++i) {
    const int s = l15 * 16 + i;
    in[i] = *(const u16x4*)(tl + s * 72 + ((q ^ l15) << 2));
  }
#pragma unroll
  for (int j = 0; j < 4; ++j) {
    u16x8 o0, o1;
#pragma unroll
    for (int i = 0; i < 8; ++i) {
      o0[i] = in[i][j];
      o1[i] = in[8 + i][j];
    }
    unsigned short* dp = dst + (size_t)(d0 + q * 4 + j) * dstld + s0 + l15 * 16;
    *(u16x8*)dp = o0;
    *(u16x8*)(dp + 8) = o1;
  }
}

// ---------------------------------------------------------------------------
extern "C" void kernel_launch(void* const* d_in, const int* in_sizes, int n_in,
                              void* d_out, int out_size, void* d_ws, size_t ws_size,
                              hipStream_t stream) {
  const float* x = (const float*)d_in[0];
  const float* Wq = (const float*)d_in[1];
  const float* bq = (const float*)d_in[2];
  const float* Wk = (const float*)d_in[3];
  const float* bk = (const float*)d_in[4];
  const float* Wv = (const float*)d_in[5];
  const float* bv = (const float*)d_in[6];
  const float* Wo = (const float*)d_in[7];
  const float* bo = (const float*)d_in[8];
  const float* E = (const float*)d_in[9];
  const float* Fp = (const float*)d_in[10];

  char* ws = (char*)d_ws;
  size_t off = 0;
  auto alloc = [&](size_t bytes) {
    char* p = ws + off;
    off += (bytes + 255) & ~(size_t)255;
    return p;
  };
  unsigned short* xb = (unsigned short*)alloc(33554432ull * 2);
  unsigned short* xbT = (unsigned short*)alloc(33554432ull * 2);
  unsigned short* Qb = (unsigned short*)alloc(33554432ull * 2);
  unsigned short* Wqkvt = (unsigned short*)alloc(3145728ull * 2);
  unsigned short* Wot = (unsigned short*)alloc(1048576ull * 2);
  unsigned short* Et = (unsigned short*)alloc(1048576ull * 2);
  unsigned short* Ft = (unsigned short*)alloc(1048576ull * 2);
  unsigned short* xEF = (unsigned short*)alloc(4194304ull * 2);
  unsigned short* Kp = (unsigned short*)alloc(2097152ull * 2);
  unsigned short* VpT = (unsigned short*)alloc(2097152ull * 2);
  float* pxef = (float*)alloc(16777216ull * 4);
  float* biasq = (float*)alloc(3072 * 4);
  float* part = (float*)alloc(8192 * 4);
  float* sEF = (float*)alloc(512 * 4);
  (void)in_sizes; (void)n_in; (void)out_size; (void)ws_size;

  k_colsum1<<<dim3(16, 2), 256, 0, stream>>>(E, Fp, part);
  k_cvt_xt<<<2048, 256, 0, stream>>>(x, xb, xbT);
  k_prep<<<398, 256, 0, stream>>>(Wq, Wk, Wv, Wo, E, Fp, bq, bk, bv, part,
                                  Wqkvt, Wot, Et, Ft, biasq, sEF);
  k_gemm_q<<<dim3(4, 128), 512, 0, stream>>>(xb, Wqkvt, biasq, Qb);
  k_gemm_xef<<<dim3(4, 1, 64), 512, 0, stream>>>(Et, Ft, xbT, pxef);
  k_xef_red<<<4096, 256, 0, stream>>>(pxef, xEF);
  k_kpvp2<<<dim3(8, 2, 16), 256, 0, stream>>>(xEF, Wqkvt, biasq, sEF, Kp, VpT);
  k_attn<<<dim3(2, 16, 8), 512, 0, stream>>>(Qb, Kp, VpT, xb);
  k_gemm_out<<<dim3(4, 128), 512, 0, stream>>>(xb, Wot, bo, (float*)d_out);
}